// Round 1
// baseline (429.834 us; speedup 1.0000x reference)
//
#include <hip/hip_runtime.h>

#define T_TRIALS 1000
#define B_SIZE   8192
#define P_SIZE   1024
#define UNR      8
#define ER_DECAY 0.999f

__device__ __forceinline__ float sp_(float x){ return __logf(1.0f + __expf(x)); }   // softplus
__device__ __forceinline__ float sg_(float x){ return 1.0f / (1.0f + __expf(-x)); } // sigmoid
__device__ __forceinline__ float clampf(float x, float lo, float hi){ return fminf(fmaxf(x, lo), hi); }

__global__ __launch_bounds__(64)
void castro_scan(const float* __restrict__ params,   // (13, P)
                 const float* __restrict__ rewards,  // (T, B)
                 const int*   __restrict__ choices,  // (T, B)
                 const int*   __restrict__ pids,     // (B,)
                 float*       __restrict__ out)      // (T, B, 4)
{
    const int b = blockIdx.x * blockDim.x + threadIdx.x;
    if (b >= B_SIZE) return;

    const int pid = pids[b];

    // ---- parameter transform (matches _transform_params) ----
    float p[13];
    #pragma unroll
    for (int k = 0; k < 13; ++k)
        p[k] = clampf(params[k * P_SIZE + pid], -5.0f, 5.0f);

    const float beta_r   = clampf(sp_(p[0]), 0.01f, 20.0f);
    const float lapse    = clampf(sg_(p[1]), 0.01f, 0.99f);
    const float prior    = clampf(sp_(p[2]), 0.01f, 0.99f);
    const float alpha_er = clampf(sg_(p[3]), 0.01f, 0.99f);
    const float decay    = clampf(sg_(p[4]), 0.01f, 0.99f);
    const float ab1      = p[5];
    const float ab2      = p[6];
    const float perv     = sp_(p[7]);
    const float sw       = p[8];
    const float gam      = sp_(p[10]);
    const float temp     = clampf(sp_(p[11]) + 1e-6f, 1e-6f, 100.0f);
    const float beta_p   = sp_(p[12]);

    const float bt  = beta_r / temp;      // beta_r / temp
    const float ol  = 1.0f - lapse;
    const float la4 = 0.25f * lapse;
    const float gp1 = 1.0f + gam;

    // ---- state (all registers) ----
    float q0 = prior, q1 = prior, q2 = prior, q3 = prior;
    float n0 = 0.f, n1 = 0.f, n2 = 0.f, n3 = 0.f;   // cumulative choice counts
    int   old_c = -1;
    float tsls = 0.0f;
    float er   = alpha_er;

    const int*   cp = choices + b;
    const float* rp = rewards + b;
    float4*      op = reinterpret_cast<float4*>(out) + b;   // element (t*B + b)

    // prefetch group 0
    int   cbuf[UNR];
    float rbuf[UNR];
    #pragma unroll
    for (int i = 0; i < UNR; ++i) {
        cbuf[i] = cp[i * B_SIZE];
        rbuf[i] = rp[i * B_SIZE];
    }

    for (int t0 = 0; t0 < T_TRIALS; t0 += UNR) {
        int   cc[UNR];
        float rr[UNR];
        #pragma unroll
        for (int i = 0; i < UNR; ++i) { cc[i] = cbuf[i]; rr[i] = rbuf[i]; }

        if (t0 + UNR < T_TRIALS) {
            #pragma unroll
            for (int i = 0; i < UNR; ++i) {
                cbuf[i] = cp[(t0 + UNR + i) * B_SIZE];
                rbuf[i] = rp[(t0 + UNR + i) * B_SIZE];
            }
        }

        #pragma unroll
        for (int i = 0; i < UNR; ++i) {
            const int   c = cc[i];
            const float r = rr[i];

            const float target = fmaf(r, gp1, -gam);     // r - gam*(1-r)

            const bool e0 = (c == 0), e1 = (c == 1), e2 = (c == 2), e3 = (c == 3);
            q0 = e0 ? target : q0;
            q1 = e1 ? target : q1;
            q2 = e2 ? target : q2;
            q3 = e3 ? target : q3;

            const bool same = (c == old_c);
            tsls = same ? (tsls + 1.0f) : 0.0f;
            er  *= ER_DECAY;

            n0 += e0 ? 1.0f : 0.0f;
            n1 += e1 ? 1.0f : 0.0f;
            n2 += e2 ? 1.0f : 0.0f;
            n3 += e3 ? 1.0f : 0.0f;

            const float qm = 0.25f * ((q0 + q1) + (q2 + q3));
            q0 = decay * fmaf(er, qm - q0, q0);
            q1 = decay * fmaf(er, qm - q1, q1);
            q2 = decay * fmaf(er, qm - q2, q2);
            q3 = decay * fmaf(er, qm - q3, q3);

            float s0 = fmaf(bt, q0, beta_p * __logf(1.0f + n0));
            float s1 = fmaf(bt, q1, beta_p * __logf(1.0f + n1));
            float s2 = fmaf(bt, q2, beta_p * __logf(1.0f + n2));
            float s3 = fmaf(bt, q3, beta_p * __logf(1.0f + n3));

            const float m  = fmaxf(fmaxf(s0, s1), fmaxf(s2, s3));
            const float x0 = __expf(s0 - m);
            const float x1 = __expf(s1 - m);
            const float x2 = __expf(s2 - m);
            const float x3 = __expf(s3 - m);
            const float inv = __builtin_amdgcn_rcpf((x0 + x1) + (x2 + x3));
            const float sc  = ol * inv;

            float l0 = __logf(fmaf(sc, x0, la4));
            float l1 = __logf(fmaf(sc, x1, la4));
            float l2 = __logf(fmaf(sc, x2, la4));
            float l3 = __logf(fmaf(sc, x3, la4));

            const float bonus = (same ? perv : sw) + __logf(tsls + 1.0f);
            l0 += e0 ? bonus : 0.0f;
            l1 += e1 ? bonus : 0.0f;
            l2 += e2 ? bonus : 0.0f;
            l3 += e3 ? bonus : 0.0f;

            l0 += (old_c == 0) ? ab1 : 0.0f;
            l1 += (old_c == 1) ? ab1 : 0.0f;
            l2 += (old_c == 2) ? ab1 : 0.0f;
            l3 += (old_c == 3) ? ab1 : 0.0f;

            const int c2 = (c + 2) & 3;
            l0 += (c2 == 0) ? ab2 : 0.0f;
            l1 += (c2 == 1) ? ab2 : 0.0f;
            l2 += (c2 == 2) ? ab2 : 0.0f;
            l3 += (c2 == 3) ? ab2 : 0.0f;

            op[(size_t)(t0 + i) * B_SIZE] = make_float4(l0, l1, l2, l3);

            old_c = c;
        }
    }
}

extern "C" void kernel_launch(void* const* d_in, const int* in_sizes, int n_in,
                              void* d_out, int out_size, void* d_ws, size_t ws_size,
                              hipStream_t stream)
{
    const float* params  = (const float*)d_in[0];
    const float* rewards = (const float*)d_in[1];
    const int*   choices = (const int*)  d_in[2];
    const int*   pids    = (const int*)  d_in[3];
    float*       out     = (float*)d_out;

    dim3 block(64);
    dim3 grid(B_SIZE / 64);
    hipLaunchKernelGGL(castro_scan, grid, block, 0, stream,
                       params, rewards, choices, pids, out);
}

// Round 2
// 93.360 us; speedup vs baseline: 4.6040x; 4.6040x over previous
//
#include <hip/hip_runtime.h>

#define T_TRIALS 1000
#define B_SIZE   8192
#define P_SIZE   1024
#define ER_DECAY 0.999f
#define LN_ER_DECAY (-1.0005003335835335e-3f)

__device__ __forceinline__ float sp_(float x){ return __logf(1.0f + __expf(x)); }   // softplus
__device__ __forceinline__ float sg_(float x){ return 1.0f / (1.0f + __expf(-x)); } // sigmoid
__device__ __forceinline__ float clampf(float x, float lo, float hi){ return fminf(fmaxf(x, lo), hi); }

// ---------------------------------------------------------------------------
// Kernel 1a: per-chunk affine map composition.
// State map per step:  q' = (I - diag(oh)) q + oh*target ; q'' = S q' ; q''' = d q''
// where S = (1-er) I + (er/4) J.  Compose over the chunk into (M, b).
// Also: per-action counts within chunk, trailing run length + last choice.
// ---------------------------------------------------------------------------
__global__ __launch_bounds__(256)
void castro_chunkmap(const float* __restrict__ params,
                     const float* __restrict__ rewards,
                     const int*   __restrict__ choices,
                     const int*   __restrict__ pids,
                     float4*      __restrict__ stageA,   // [6][nmaps*B]
                     int chunk, int nmaps)
{
    const int b = blockIdx.x * 256 + threadIdx.x;
    const int k = blockIdx.y;
    const int pid = pids[b];

    const float p3  = clampf(params[ 3 * P_SIZE + pid], -5.0f, 5.0f);
    const float p4  = clampf(params[ 4 * P_SIZE + pid], -5.0f, 5.0f);
    const float p10 = clampf(params[10 * P_SIZE + pid], -5.0f, 5.0f);
    const float alpha_er = clampf(sg_(p3), 0.01f, 0.99f);
    const float decay    = clampf(sg_(p4), 0.01f, 0.99f);
    const float gam      = sp_(p10);
    const float gp1      = 1.0f + gam;

    const int t0 = k * chunk;
    float er = alpha_er * __expf((float)t0 * LN_ER_DECAY);

    float m00=1.f,m01=0.f,m02=0.f,m03=0.f;
    float m10=0.f,m11=1.f,m12=0.f,m13=0.f;
    float m20=0.f,m21=0.f,m22=1.f,m23=0.f;
    float m30=0.f,m31=0.f,m32=0.f,m33=1.f;
    float b0=0.f,b1=0.f,b2=0.f,b3=0.f;
    int   c0=0,c1=0,c2=0,c3=0;
    int   run=0, last=-1;

    const int*   cp = choices + (size_t)t0 * B_SIZE + b;
    const float* rp = rewards + (size_t)t0 * B_SIZE + b;

    int   cbuf[8]; float rbuf[8];
    #pragma unroll
    for (int i = 0; i < 8; ++i) { cbuf[i] = cp[(size_t)i * B_SIZE]; rbuf[i] = rp[(size_t)i * B_SIZE]; }

    for (int tt = 0; tt < chunk; tt += 8) {
        int cc[8]; float rr[8];
        #pragma unroll
        for (int i = 0; i < 8; ++i) { cc[i] = cbuf[i]; rr[i] = rbuf[i]; }
        if (tt + 8 < chunk) {
            #pragma unroll
            for (int i = 0; i < 8; ++i) {
                cbuf[i] = cp[(size_t)(tt + 8 + i) * B_SIZE];
                rbuf[i] = rp[(size_t)(tt + 8 + i) * B_SIZE];
            }
        }
        #pragma unroll
        for (int i = 0; i < 8; ++i) {
            const int   c = cc[i];
            const float r = rr[i];
            er *= ER_DECAY;
            const float target = fmaf(r, gp1, -gam);
            const bool e0=(c==0), e1=(c==1), e2=(c==2), e3=(c==3);

            m00=e0?0.f:m00; m01=e0?0.f:m01; m02=e0?0.f:m02; m03=e0?0.f:m03; b0=e0?target:b0;
            m10=e1?0.f:m10; m11=e1?0.f:m11; m12=e1?0.f:m12; m13=e1?0.f:m13; b1=e1?target:b1;
            m20=e2?0.f:m20; m21=e2?0.f:m21; m22=e2?0.f:m22; m23=e2?0.f:m23; b2=e2?target:b2;
            m30=e3?0.f:m30; m31=e3?0.f:m31; m32=e3?0.f:m32; m33=e3?0.f:m33; b3=e3?target:b3;

            const float s0=(m00+m10)+(m20+m30);
            const float s1=(m01+m11)+(m21+m31);
            const float s2=(m02+m12)+(m22+m32);
            const float s3=(m03+m13)+(m23+m33);
            const float sb=(b0+b1)+(b2+b3);
            const float a  = decay * (1.0f - er);
            const float e4 = decay * er * 0.25f;

            m00=fmaf(e4,s0,a*m00); m01=fmaf(e4,s1,a*m01); m02=fmaf(e4,s2,a*m02); m03=fmaf(e4,s3,a*m03);
            m10=fmaf(e4,s0,a*m10); m11=fmaf(e4,s1,a*m11); m12=fmaf(e4,s2,a*m12); m13=fmaf(e4,s3,a*m13);
            m20=fmaf(e4,s0,a*m20); m21=fmaf(e4,s1,a*m21); m22=fmaf(e4,s2,a*m22); m23=fmaf(e4,s3,a*m23);
            m30=fmaf(e4,s0,a*m30); m31=fmaf(e4,s1,a*m31); m32=fmaf(e4,s2,a*m32); m33=fmaf(e4,s3,a*m33);
            b0=fmaf(e4,sb,a*b0); b1=fmaf(e4,sb,a*b1); b2=fmaf(e4,sb,a*b2); b3=fmaf(e4,sb,a*b3);

            c0 += e0; c1 += e1; c2 += e2; c3 += e3;
            run = (c == last) ? run + 1 : 1;
            last = c;
        }
    }

    const size_t idx    = (size_t)k * B_SIZE + b;
    const size_t stride = (size_t)nmaps * B_SIZE;
    stageA[0*stride+idx] = make_float4(m00,m01,m02,m03);
    stageA[1*stride+idx] = make_float4(m10,m11,m12,m13);
    stageA[2*stride+idx] = make_float4(m20,m21,m22,m23);
    stageA[3*stride+idx] = make_float4(m30,m31,m32,m33);
    stageA[4*stride+idx] = make_float4(b0,b1,b2,b3);
    const unsigned meta0 = (unsigned)c0 | ((unsigned)c1<<8) | ((unsigned)c2<<16) | ((unsigned)c3<<24);
    const unsigned meta1 = (unsigned)last | ((unsigned)run<<8);
    stageA[5*stride+idx] = make_float4(__uint_as_float(meta0), __uint_as_float(meta1), 0.f, 0.f);
}

// ---------------------------------------------------------------------------
// Kernel 1b: sequential combine over chunk maps -> checkpoints.
// checkpoint[k] = carry entering step (k+1)*chunk, for k in [0, nmaps)
// ---------------------------------------------------------------------------
__global__ __launch_bounds__(256)
void castro_combine(const float* __restrict__ params,
                    const int*   __restrict__ pids,
                    const float4* __restrict__ stageA,
                    float4*      __restrict__ cps,      // 2 float4 per (k,b)
                    int chunk, int nmaps)
{
    const int b = blockIdx.x * 256 + threadIdx.x;
    const int pid = pids[b];
    const float p2 = clampf(params[2 * P_SIZE + pid], -5.0f, 5.0f);
    const float p3 = clampf(params[3 * P_SIZE + pid], -5.0f, 5.0f);
    const float prior    = clampf(sp_(p2), 0.01f, 0.99f);
    const float alpha_er = clampf(sg_(p3), 0.01f, 0.99f);

    float q0=prior, q1=prior, q2=prior, q3=prior;
    int   n0=0,n1=0,n2=0,n3=0;
    int   g_run=0, g_last=-1;

    const size_t stride = (size_t)nmaps * B_SIZE;

    float4 A0=stageA[0*stride+b], A1=stageA[1*stride+b], A2=stageA[2*stride+b],
           A3=stageA[3*stride+b], A4=stageA[4*stride+b], A5=stageA[5*stride+b];

    for (int k = 0; k < nmaps; ++k) {
        const float4 r0=A0, r1=A1, r2=A2, r3=A3, r4=A4, r5=A5;
        if (k + 1 < nmaps) {
            const size_t i2 = (size_t)(k+1)*B_SIZE + b;
            A0=stageA[0*stride+i2]; A1=stageA[1*stride+i2]; A2=stageA[2*stride+i2];
            A3=stageA[3*stride+i2]; A4=stageA[4*stride+i2]; A5=stageA[5*stride+i2];
        }
        const float nq0 = fmaf(r0.w,q3, fmaf(r0.z,q2, fmaf(r0.y,q1, fmaf(r0.x,q0, r4.x))));
        const float nq1 = fmaf(r1.w,q3, fmaf(r1.z,q2, fmaf(r1.y,q1, fmaf(r1.x,q0, r4.y))));
        const float nq2 = fmaf(r2.w,q3, fmaf(r2.z,q2, fmaf(r2.y,q1, fmaf(r2.x,q0, r4.z))));
        const float nq3 = fmaf(r3.w,q3, fmaf(r3.z,q2, fmaf(r3.y,q1, fmaf(r3.x,q0, r4.w))));
        q0=nq0; q1=nq1; q2=nq2; q3=nq3;

        const unsigned meta0 = __float_as_uint(r5.x);
        const unsigned meta1 = __float_as_uint(r5.y);
        n0 += (int)( meta0        & 255u);
        n1 += (int)((meta0 >> 8 ) & 255u);
        n2 += (int)((meta0 >> 16) & 255u);
        n3 += (int)( meta0 >> 24        );
        const int last = (int)(meta1 & 255u);
        const int rn   = (int)(meta1 >> 8);
        g_run  = (rn == chunk && last == g_last) ? g_run + chunk : rn;
        g_last = last;

        const float er_b = alpha_er * __expf((float)((k+1)*chunk) * LN_ER_DECAY);
        const int   tsls = g_run - 1;

        const size_t ci = 2u * ((size_t)k * B_SIZE + b);
        cps[ci]   = make_float4(q0,q1,q2,q3);
        cps[ci+1] = make_float4(er_b,
                                __uint_as_float((unsigned)n0 | ((unsigned)n1<<16)),
                                __uint_as_float((unsigned)n2 | ((unsigned)n3<<16)),
                                __uint_as_float((unsigned)tsls | ((unsigned)g_last<<16)));
    }
}

// ---------------------------------------------------------------------------
// Kernel 2: per-chunk logit replay + output.
// ---------------------------------------------------------------------------
__global__ __launch_bounds__(256)
void castro_emit(const float* __restrict__ params,
                 const float* __restrict__ rewards,
                 const int*   __restrict__ choices,
                 const int*   __restrict__ pids,
                 const float4* __restrict__ cps,
                 float4*      __restrict__ out4,
                 int chunk)
{
    __shared__ float ln1p[1024];
    for (int i = threadIdx.x; i < 1024; i += 256) ln1p[i] = __logf(1.0f + (float)i);
    __syncthreads();

    const int b = blockIdx.x * 256 + threadIdx.x;
    const int k = blockIdx.y;
    const int t0 = k * chunk;
    const int t1 = min(T_TRIALS, t0 + chunk);
    const int pid = pids[b];

    float p[13];
    #pragma unroll
    for (int kk = 0; kk < 13; ++kk)
        p[kk] = clampf(params[kk * P_SIZE + pid], -5.0f, 5.0f);

    const float beta_r   = clampf(sp_(p[0]), 0.01f, 20.0f);
    const float lapse    = clampf(sg_(p[1]), 0.01f, 0.99f);
    const float prior    = clampf(sp_(p[2]), 0.01f, 0.99f);
    const float alpha_er = clampf(sg_(p[3]), 0.01f, 0.99f);
    const float decay    = clampf(sg_(p[4]), 0.01f, 0.99f);
    const float ab1      = p[5];
    const float ab2      = p[6];
    const float perv     = sp_(p[7]);
    const float sw       = p[8];
    const float gam      = sp_(p[10]);
    const float temp     = clampf(sp_(p[11]) + 1e-6f, 1e-6f, 100.0f);
    const float beta_p   = sp_(p[12]);

    const float bt  = beta_r / temp;
    const float ol  = 1.0f - lapse;
    const float la4 = 0.25f * lapse;
    const float gp1 = 1.0f + gam;

    float q0,q1,q2,q3, er;
    int   n0,n1,n2,n3, tsls_i, old_c;
    if (k == 0) {
        q0=q1=q2=q3=prior; n0=n1=n2=n3=0; tsls_i=0; old_c=-1; er=alpha_er;
    } else {
        const size_t ci = 2u * ((size_t)(k-1) * B_SIZE + b);
        const float4 s0 = cps[ci];
        const float4 s1 = cps[ci+1];
        q0=s0.x; q1=s0.y; q2=s0.z; q3=s0.w;
        er = s1.x;
        const unsigned u1=__float_as_uint(s1.y), u2=__float_as_uint(s1.z), u3=__float_as_uint(s1.w);
        n0=(int)(u1&0xFFFFu); n1=(int)(u1>>16);
        n2=(int)(u2&0xFFFFu); n3=(int)(u2>>16);
        tsls_i=(int)(u3&0xFFFFu); old_c=(int)(u3>>16);
    }
    float ln0=ln1p[n0], ln1_=ln1p[n1], ln2_=ln1p[n2], ln3_=ln1p[n3];

    const int*   cp = choices + (size_t)t0 * B_SIZE + b;
    const float* rp = rewards + (size_t)t0 * B_SIZE + b;
    float4*      op = out4 + (size_t)t0 * B_SIZE + b;
    const int nsteps = t1 - t0;   // multiple of 8

    int   cbuf[8]; float rbuf[8];
    #pragma unroll
    for (int i = 0; i < 8; ++i) { cbuf[i] = cp[(size_t)i*B_SIZE]; rbuf[i] = rp[(size_t)i*B_SIZE]; }

    for (int tt = 0; tt < nsteps; tt += 8) {
        int cc[8]; float rr[8];
        #pragma unroll
        for (int i = 0; i < 8; ++i) { cc[i] = cbuf[i]; rr[i] = rbuf[i]; }
        if (tt + 8 < nsteps) {
            #pragma unroll
            for (int i = 0; i < 8; ++i) {
                cbuf[i] = cp[(size_t)(tt+8+i)*B_SIZE];
                rbuf[i] = rp[(size_t)(tt+8+i)*B_SIZE];
            }
        }
        #pragma unroll
        for (int i = 0; i < 8; ++i) {
            const int   c = cc[i];
            const float r = rr[i];
            const float target = fmaf(r, gp1, -gam);
            const bool e0=(c==0), e1=(c==1), e2=(c==2), e3=(c==3);
            q0 = e0 ? target : q0;
            q1 = e1 ? target : q1;
            q2 = e2 ? target : q2;
            q3 = e3 ? target : q3;

            const bool same = (c == old_c);
            tsls_i = same ? tsls_i + 1 : 0;
            er *= ER_DECAY;

            const int nch = e0 ? n0+1 : (e1 ? n1+1 : (e2 ? n2+1 : n3+1));
            const float lnch = ln1p[nch];
            n0 += e0; n1 += e1; n2 += e2; n3 += e3;
            ln0  = e0 ? lnch : ln0;
            ln1_ = e1 ? lnch : ln1_;
            ln2_ = e2 ? lnch : ln2_;
            ln3_ = e3 ? lnch : ln3_;

            const float qm = 0.25f * ((q0+q1)+(q2+q3));
            q0 = decay * fmaf(er, qm - q0, q0);
            q1 = decay * fmaf(er, qm - q1, q1);
            q2 = decay * fmaf(er, qm - q2, q2);
            q3 = decay * fmaf(er, qm - q3, q3);

            const float s0 = fmaf(bt, q0, beta_p * ln0);
            const float s1 = fmaf(bt, q1, beta_p * ln1_);
            const float s2 = fmaf(bt, q2, beta_p * ln2_);
            const float s3 = fmaf(bt, q3, beta_p * ln3_);

            const float m  = fmaxf(fmaxf(s0, s1), fmaxf(s2, s3));
            const float x0 = __expf(s0 - m);
            const float x1 = __expf(s1 - m);
            const float x2 = __expf(s2 - m);
            const float x3 = __expf(s3 - m);
            const float inv = __builtin_amdgcn_rcpf((x0+x1)+(x2+x3));
            const float sc  = ol * inv;

            float l0 = __logf(fmaf(sc, x0, la4));
            float l1 = __logf(fmaf(sc, x1, la4));
            float l2 = __logf(fmaf(sc, x2, la4));
            float l3 = __logf(fmaf(sc, x3, la4));

            const float bonus = (same ? perv : sw) + ln1p[tsls_i];
            l0 += e0 ? bonus : 0.0f;
            l1 += e1 ? bonus : 0.0f;
            l2 += e2 ? bonus : 0.0f;
            l3 += e3 ? bonus : 0.0f;

            l0 += (old_c == 0) ? ab1 : 0.0f;
            l1 += (old_c == 1) ? ab1 : 0.0f;
            l2 += (old_c == 2) ? ab1 : 0.0f;
            l3 += (old_c == 3) ? ab1 : 0.0f;

            const int c2 = (c + 2) & 3;
            l0 += (c2 == 0) ? ab2 : 0.0f;
            l1 += (c2 == 1) ? ab2 : 0.0f;
            l2 += (c2 == 2) ? ab2 : 0.0f;
            l3 += (c2 == 3) ? ab2 : 0.0f;

            op[(size_t)(tt + i) * B_SIZE] = make_float4(l0, l1, l2, l3);
            old_c = c;
        }
    }
}

// ---------------------------------------------------------------------------
// Fallback: round-1 monolithic scan (only if workspace is too small).
// ---------------------------------------------------------------------------
__global__ __launch_bounds__(64)
void castro_scan(const float* __restrict__ params,
                 const float* __restrict__ rewards,
                 const int*   __restrict__ choices,
                 const int*   __restrict__ pids,
                 float*       __restrict__ out)
{
    const int b = blockIdx.x * blockDim.x + threadIdx.x;
    if (b >= B_SIZE) return;
    const int pid = pids[b];
    float p[13];
    #pragma unroll
    for (int kk = 0; kk < 13; ++kk)
        p[kk] = clampf(params[kk * P_SIZE + pid], -5.0f, 5.0f);
    const float beta_r   = clampf(sp_(p[0]), 0.01f, 20.0f);
    const float lapse    = clampf(sg_(p[1]), 0.01f, 0.99f);
    const float prior    = clampf(sp_(p[2]), 0.01f, 0.99f);
    const float alpha_er = clampf(sg_(p[3]), 0.01f, 0.99f);
    const float decay    = clampf(sg_(p[4]), 0.01f, 0.99f);
    const float ab1 = p[5], ab2 = p[6];
    const float perv = sp_(p[7]), sw = p[8];
    const float gam  = sp_(p[10]);
    const float temp = clampf(sp_(p[11]) + 1e-6f, 1e-6f, 100.0f);
    const float beta_p = sp_(p[12]);
    const float bt = beta_r / temp, ol = 1.0f - lapse, la4 = 0.25f * lapse, gp1 = 1.0f + gam;

    float q0=prior,q1=prior,q2=prior,q3=prior;
    float n0=0,n1=0,n2=0,n3=0;
    int old_c=-1; float tsls=0.0f, er=alpha_er;
    const int* cp = choices + b;
    const float* rp = rewards + b;
    float4* op = reinterpret_cast<float4*>(out) + b;
    for (int t = 0; t < T_TRIALS; ++t) {
        const int c = cp[(size_t)t*B_SIZE];
        const float r = rp[(size_t)t*B_SIZE];
        const float target = fmaf(r, gp1, -gam);
        const bool e0=(c==0),e1=(c==1),e2=(c==2),e3=(c==3);
        q0=e0?target:q0; q1=e1?target:q1; q2=e2?target:q2; q3=e3?target:q3;
        const bool same = (c == old_c);
        tsls = same ? tsls + 1.0f : 0.0f;
        er *= ER_DECAY;
        n0+=e0?1.f:0.f; n1+=e1?1.f:0.f; n2+=e2?1.f:0.f; n3+=e3?1.f:0.f;
        const float qm = 0.25f*((q0+q1)+(q2+q3));
        q0 = decay*fmaf(er, qm-q0, q0); q1 = decay*fmaf(er, qm-q1, q1);
        q2 = decay*fmaf(er, qm-q2, q2); q3 = decay*fmaf(er, qm-q3, q3);
        float s0 = fmaf(bt,q0,beta_p*__logf(1.f+n0));
        float s1 = fmaf(bt,q1,beta_p*__logf(1.f+n1));
        float s2 = fmaf(bt,q2,beta_p*__logf(1.f+n2));
        float s3 = fmaf(bt,q3,beta_p*__logf(1.f+n3));
        const float m = fmaxf(fmaxf(s0,s1),fmaxf(s2,s3));
        const float x0=__expf(s0-m),x1=__expf(s1-m),x2=__expf(s2-m),x3=__expf(s3-m);
        const float inv=__builtin_amdgcn_rcpf((x0+x1)+(x2+x3));
        const float sc=ol*inv;
        float l0=__logf(fmaf(sc,x0,la4)), l1=__logf(fmaf(sc,x1,la4));
        float l2=__logf(fmaf(sc,x2,la4)), l3=__logf(fmaf(sc,x3,la4));
        const float bonus=(same?perv:sw)+__logf(tsls+1.0f);
        l0+=e0?bonus:0.f; l1+=e1?bonus:0.f; l2+=e2?bonus:0.f; l3+=e3?bonus:0.f;
        l0+=(old_c==0)?ab1:0.f; l1+=(old_c==1)?ab1:0.f; l2+=(old_c==2)?ab1:0.f; l3+=(old_c==3)?ab1:0.f;
        const int c2=(c+2)&3;
        l0+=(c2==0)?ab2:0.f; l1+=(c2==1)?ab2:0.f; l2+=(c2==2)?ab2:0.f; l3+=(c2==3)?ab2:0.f;
        op[(size_t)t*B_SIZE] = make_float4(l0,l1,l2,l3);
        old_c=c;
    }
}

extern "C" void kernel_launch(void* const* d_in, const int* in_sizes, int n_in,
                              void* d_out, int out_size, void* d_ws, size_t ws_size,
                              hipStream_t stream)
{
    const float* params  = (const float*)d_in[0];
    const float* rewards = (const float*)d_in[1];
    const int*   choices = (const int*)  d_in[2];
    const int*   pids    = (const int*)  d_in[3];

    size_t K = ws_size / ((size_t)B_SIZE * 128);
    if (K > 25) K = 25;

    if (K < 8) {
        hipLaunchKernelGGL(castro_scan, dim3(B_SIZE/64), dim3(64), 0, stream,
                           params, rewards, choices, pids, (float*)d_out);
        return;
    }

    const int chunk = (int)((((size_t)T_TRIALS + K - 1) / K + 7) & ~(size_t)7);
    const int Keff  = (T_TRIALS + chunk - 1) / chunk;
    const int nmaps = Keff - 1;

    float4* stageA = (float4*)d_ws;
    float4* cps    = stageA + (size_t)6 * nmaps * B_SIZE;

    hipLaunchKernelGGL(castro_chunkmap, dim3(B_SIZE/256, nmaps), dim3(256), 0, stream,
                       params, rewards, choices, pids, stageA, chunk, nmaps);
    hipLaunchKernelGGL(castro_combine, dim3(B_SIZE/256), dim3(256), 0, stream,
                       params, pids, stageA, cps, chunk, nmaps);
    hipLaunchKernelGGL(castro_emit, dim3(B_SIZE/256, Keff), dim3(256), 0, stream,
                       params, rewards, choices, pids, cps, (float4*)d_out, chunk);
}

// Round 4
// 81.243 us; speedup vs baseline: 5.2907x; 1.1491x over previous
//
#include <hip/hip_runtime.h>
#include <stdint.h>

#define T_TRIALS 1000
#define B_SIZE   8192
#define P_SIZE   1024
#define CHUNK    40            // steps per chunk (fixed-geometry path)
#define KCH      25            // number of chunks (25*40 = 1000)
#define NMAPS    24            // KCH-1 maps feed the combine
#define GRP      5             // CHUNK/8 packed u32 groups per chunk
#define ER_DECAY 0.999f
#define LN_ER_DECAY (-1.0005003335835335e-3f)

typedef float f32x4_t __attribute__((ext_vector_type(4)));

__device__ __forceinline__ float sp_(float x){ return __logf(1.0f + __expf(x)); }   // softplus
__device__ __forceinline__ float sg_(float x){ return 1.0f / (1.0f + __expf(-x)); } // sigmoid
__device__ __forceinline__ float clampf(float x, float lo, float hi){ return fminf(fmaxf(x, lo), hi); }

// ===========================================================================
// FIXED-GEOMETRY PATH (K=25, CHUNK=40) with 4-bit (choice,reward) packing
// ===========================================================================

// Kernel 1a: per-chunk affine map composition + packing.
__global__ __launch_bounds__(256)
void castro_chunkmap_p(const float* __restrict__ params,
                       const float* __restrict__ rewards,
                       const int*   __restrict__ choices,
                       const int*   __restrict__ pids,
                       float4*      __restrict__ stageA,   // [6][NMAPS*B]
                       uint32_t*    __restrict__ packed)   // [KCH*GRP*B]
{
    const int b = blockIdx.x * 256 + threadIdx.x;
    const int k = blockIdx.y;
    const int t0 = k * CHUNK;

    const int*   cp = choices + (size_t)t0 * B_SIZE + b;
    const float* rp = rewards + (size_t)t0 * B_SIZE + b;
    uint32_t*    pk = packed + ((size_t)k * GRP) * B_SIZE + b;

    if (k == NMAPS) {   // last chunk: its map is never used — pack only
        #pragma unroll
        for (int g = 0; g < GRP; ++g) {
            uint32_t gw = 0;
            #pragma unroll
            for (int i = 0; i < 8; ++i) {
                const int   c = cp[(size_t)(g*8 + i) * B_SIZE];
                const float r = rp[(size_t)(g*8 + i) * B_SIZE];
                gw |= ((uint32_t)c | (r > 0.5f ? 4u : 0u)) << (4*i);
            }
            pk[(size_t)g * B_SIZE] = gw;
        }
        return;
    }

    const int pid = pids[b];
    const float p3  = clampf(params[ 3 * P_SIZE + pid], -5.0f, 5.0f);
    const float p4  = clampf(params[ 4 * P_SIZE + pid], -5.0f, 5.0f);
    const float p10 = clampf(params[10 * P_SIZE + pid], -5.0f, 5.0f);
    const float alpha_er = clampf(sg_(p3), 0.01f, 0.99f);
    const float decay    = clampf(sg_(p4), 0.01f, 0.99f);
    const float gam      = sp_(p10);
    const float gp1      = 1.0f + gam;

    float er = alpha_er * __expf((float)t0 * LN_ER_DECAY);

    float m00=1.f,m01=0.f,m02=0.f,m03=0.f;
    float m10=0.f,m11=1.f,m12=0.f,m13=0.f;
    float m20=0.f,m21=0.f,m22=1.f,m23=0.f;
    float m30=0.f,m31=0.f,m32=0.f,m33=1.f;
    float b0=0.f,b1=0.f,b2=0.f,b3=0.f;
    int   c0=0,c1=0,c2=0,c3=0;
    int   run=0, last=-1;

    #pragma unroll
    for (int g = 0; g < GRP; ++g) {
        int cc[8]; float rr[8];
        #pragma unroll
        for (int i = 0; i < 8; ++i) {
            cc[i] = cp[(size_t)(g*8 + i) * B_SIZE];
            rr[i] = rp[(size_t)(g*8 + i) * B_SIZE];
        }
        uint32_t gw = 0;
        #pragma unroll
        for (int i = 0; i < 8; ++i) {
            const int   c = cc[i];
            const float r = rr[i];
            gw |= ((uint32_t)c | (r > 0.5f ? 4u : 0u)) << (4*i);

            er *= ER_DECAY;
            const float target = fmaf(r, gp1, -gam);
            const bool e0=(c==0), e1=(c==1), e2=(c==2), e3=(c==3);

            m00=e0?0.f:m00; m01=e0?0.f:m01; m02=e0?0.f:m02; m03=e0?0.f:m03; b0=e0?target:b0;
            m10=e1?0.f:m10; m11=e1?0.f:m11; m12=e1?0.f:m12; m13=e1?0.f:m13; b1=e1?target:b1;
            m20=e2?0.f:m20; m21=e2?0.f:m21; m22=e2?0.f:m22; m23=e2?0.f:m23; b2=e2?target:b2;
            m30=e3?0.f:m30; m31=e3?0.f:m31; m32=e3?0.f:m32; m33=e3?0.f:m33; b3=e3?target:b3;

            const float s0=(m00+m10)+(m20+m30);
            const float s1=(m01+m11)+(m21+m31);
            const float s2=(m02+m12)+(m22+m32);
            const float s3=(m03+m13)+(m23+m33);
            const float sb=(b0+b1)+(b2+b3);
            const float a  = decay * (1.0f - er);
            const float e4 = decay * er * 0.25f;

            m00=fmaf(e4,s0,a*m00); m01=fmaf(e4,s1,a*m01); m02=fmaf(e4,s2,a*m02); m03=fmaf(e4,s3,a*m03);
            m10=fmaf(e4,s0,a*m10); m11=fmaf(e4,s1,a*m11); m12=fmaf(e4,s2,a*m12); m13=fmaf(e4,s3,a*m13);
            m20=fmaf(e4,s0,a*m20); m21=fmaf(e4,s1,a*m21); m22=fmaf(e4,s2,a*m22); m23=fmaf(e4,s3,a*m23);
            m30=fmaf(e4,s0,a*m30); m31=fmaf(e4,s1,a*m31); m32=fmaf(e4,s2,a*m32); m33=fmaf(e4,s3,a*m33);
            b0=fmaf(e4,sb,a*b0); b1=fmaf(e4,sb,a*b1); b2=fmaf(e4,sb,a*b2); b3=fmaf(e4,sb,a*b3);

            c0 += e0; c1 += e1; c2 += e2; c3 += e3;
            run = (c == last) ? run + 1 : 1;
            last = c;
        }
        pk[(size_t)g * B_SIZE] = gw;
    }

    const size_t idx    = (size_t)k * B_SIZE + b;
    const size_t stride = (size_t)NMAPS * B_SIZE;
    stageA[0*stride+idx] = make_float4(m00,m01,m02,m03);
    stageA[1*stride+idx] = make_float4(m10,m11,m12,m13);
    stageA[2*stride+idx] = make_float4(m20,m21,m22,m23);
    stageA[3*stride+idx] = make_float4(m30,m31,m32,m33);
    stageA[4*stride+idx] = make_float4(b0,b1,b2,b3);
    const unsigned meta0 = (unsigned)c0 | ((unsigned)c1<<8) | ((unsigned)c2<<16) | ((unsigned)c3<<24);
    const unsigned meta1 = (unsigned)last | ((unsigned)run<<8);
    stageA[5*stride+idx] = make_float4(__uint_as_float(meta0), __uint_as_float(meta1), 0.f, 0.f);
}

// ---------------------------------------------------------------------------
// Kernel 1b: sequential combine, depth-4 software prefetch (struct-based).
// ---------------------------------------------------------------------------
struct MapSet { float4 r0, r1, r2, r3, r4, r5; };

struct CombState {
    float q0,q1,q2,q3;
    int   n0,n1,n2,n3;
    int   g_run, g_last;
};

__device__ __forceinline__ void load_set(MapSet& S, const float4* __restrict__ stageA,
                                         size_t stride, int kk, int b)
{
    const size_t i2 = (size_t)kk * B_SIZE + b;
    S.r0 = stageA[0*stride+i2]; S.r1 = stageA[1*stride+i2]; S.r2 = stageA[2*stride+i2];
    S.r3 = stageA[3*stride+i2]; S.r4 = stageA[4*stride+i2]; S.r5 = stageA[5*stride+i2];
}

__device__ __forceinline__ void step_set(const MapSet& S, CombState& st,
                                         float4* __restrict__ cps,
                                         float alpha_er, int kk, int b)
{
    const float nq0 = fmaf(S.r0.w,st.q3, fmaf(S.r0.z,st.q2, fmaf(S.r0.y,st.q1, fmaf(S.r0.x,st.q0, S.r4.x))));
    const float nq1 = fmaf(S.r1.w,st.q3, fmaf(S.r1.z,st.q2, fmaf(S.r1.y,st.q1, fmaf(S.r1.x,st.q0, S.r4.y))));
    const float nq2 = fmaf(S.r2.w,st.q3, fmaf(S.r2.z,st.q2, fmaf(S.r2.y,st.q1, fmaf(S.r2.x,st.q0, S.r4.z))));
    const float nq3 = fmaf(S.r3.w,st.q3, fmaf(S.r3.z,st.q2, fmaf(S.r3.y,st.q1, fmaf(S.r3.x,st.q0, S.r4.w))));
    st.q0=nq0; st.q1=nq1; st.q2=nq2; st.q3=nq3;

    const unsigned meta0 = __float_as_uint(S.r5.x);
    const unsigned meta1 = __float_as_uint(S.r5.y);
    st.n0 += (int)( meta0        & 255u);
    st.n1 += (int)((meta0 >> 8 ) & 255u);
    st.n2 += (int)((meta0 >> 16) & 255u);
    st.n3 += (int)( meta0 >> 24        );
    const int last = (int)(meta1 & 255u);
    const int rn   = (int)(meta1 >> 8);
    st.g_run  = (rn == CHUNK && last == st.g_last) ? st.g_run + CHUNK : rn;
    st.g_last = last;

    const float er_b = alpha_er * __expf((float)((kk+1)*CHUNK) * LN_ER_DECAY);
    const int   tsls = st.g_run - 1;

    const size_t ci = 2u * ((size_t)kk * B_SIZE + b);
    cps[ci]   = make_float4(st.q0,st.q1,st.q2,st.q3);
    cps[ci+1] = make_float4(er_b,
                            __uint_as_float((unsigned)st.n0 | ((unsigned)st.n1<<16)),
                            __uint_as_float((unsigned)st.n2 | ((unsigned)st.n3<<16)),
                            __uint_as_float((unsigned)tsls | ((unsigned)st.g_last<<16)));
}

__global__ __launch_bounds__(256)
void castro_combine_p(const float* __restrict__ params,
                      const int*   __restrict__ pids,
                      const float4* __restrict__ stageA,
                      float4*      __restrict__ cps)      // 2 float4 per (k,b)
{
    const int b = blockIdx.x * 256 + threadIdx.x;
    const int pid = pids[b];
    const float p2 = clampf(params[2 * P_SIZE + pid], -5.0f, 5.0f);
    const float p3 = clampf(params[3 * P_SIZE + pid], -5.0f, 5.0f);
    const float prior    = clampf(sp_(p2), 0.01f, 0.99f);
    const float alpha_er = clampf(sg_(p3), 0.01f, 0.99f);

    CombState st;
    st.q0=prior; st.q1=prior; st.q2=prior; st.q3=prior;
    st.n0=0; st.n1=0; st.n2=0; st.n3=0;
    st.g_run=0; st.g_last=-1;

    const size_t stride = (size_t)NMAPS * B_SIZE;

    MapSet Am, Bm, Cm, Dm;
    load_set(Am, stageA, stride, 0, b);
    load_set(Bm, stageA, stride, 1, b);
    load_set(Cm, stageA, stride, 2, b);
    load_set(Dm, stageA, stride, 3, b);

    #pragma unroll
    for (int k0 = 0; k0 < NMAPS; k0 += 4) {
        step_set(Am, st, cps, alpha_er, k0,   b); if (k0+4 < NMAPS) load_set(Am, stageA, stride, k0+4, b);
        step_set(Bm, st, cps, alpha_er, k0+1, b); if (k0+5 < NMAPS) load_set(Bm, stageA, stride, k0+5, b);
        step_set(Cm, st, cps, alpha_er, k0+2, b); if (k0+6 < NMAPS) load_set(Cm, stageA, stride, k0+6, b);
        step_set(Dm, st, cps, alpha_er, k0+3, b); if (k0+7 < NMAPS) load_set(Dm, stageA, stride, k0+7, b);
    }
}

// ---------------------------------------------------------------------------
// Kernel 2: per-chunk logit replay from packed stream.
// ---------------------------------------------------------------------------
__global__ __launch_bounds__(256)
void castro_emit_p(const float* __restrict__ params,
                   const int*   __restrict__ pids,
                   const float4* __restrict__ cps,
                   const uint32_t* __restrict__ packed,
                   float4*      __restrict__ out4)
{
    __shared__ float ln1p[1024];
    for (int i = threadIdx.x; i < 1024; i += 256) ln1p[i] = __logf(1.0f + (float)i);
    __syncthreads();

    const int b = blockIdx.x * 256 + threadIdx.x;
    const int k = blockIdx.y;
    const int t0 = k * CHUNK;
    const int pid = pids[b];

    float p[13];
    #pragma unroll
    for (int kk = 0; kk < 13; ++kk)
        p[kk] = clampf(params[kk * P_SIZE + pid], -5.0f, 5.0f);

    const float beta_r   = clampf(sp_(p[0]), 0.01f, 20.0f);
    const float lapse    = clampf(sg_(p[1]), 0.01f, 0.99f);
    const float prior    = clampf(sp_(p[2]), 0.01f, 0.99f);
    const float alpha_er = clampf(sg_(p[3]), 0.01f, 0.99f);
    const float decay    = clampf(sg_(p[4]), 0.01f, 0.99f);
    const float ab1      = p[5];
    const float ab2      = p[6];
    const float perv     = sp_(p[7]);
    const float sw       = p[8];
    const float gam      = sp_(p[10]);
    const float temp     = clampf(sp_(p[11]) + 1e-6f, 1e-6f, 100.0f);
    const float beta_p   = sp_(p[12]);

    const float bt  = beta_r / temp;
    const float ol  = 1.0f - lapse;
    const float la4 = 0.25f * lapse;
    const float gp1 = 1.0f + gam;

    float q0,q1,q2,q3, er;
    int   n0,n1,n2,n3, tsls_i, old_c;
    if (k == 0) {
        q0=q1=q2=q3=prior; n0=n1=n2=n3=0; tsls_i=0; old_c=-1; er=alpha_er;
    } else {
        const size_t ci = 2u * ((size_t)(k-1) * B_SIZE + b);
        const float4 s0 = cps[ci];
        const float4 s1 = cps[ci+1];
        q0=s0.x; q1=s0.y; q2=s0.z; q3=s0.w;
        er = s1.x;
        const unsigned u1=__float_as_uint(s1.y), u2=__float_as_uint(s1.z), u3=__float_as_uint(s1.w);
        n0=(int)(u1&0xFFFFu); n1=(int)(u1>>16);
        n2=(int)(u2&0xFFFFu); n3=(int)(u2>>16);
        tsls_i=(int)(u3&0xFFFFu); old_c=(int)(u3>>16);
    }
    float ln0=ln1p[n0], ln1_=ln1p[n1], ln2_=ln1p[n2], ln3_=ln1p[n3];

    const uint32_t* pk = packed + ((size_t)k * GRP) * B_SIZE + b;
    uint32_t gw[GRP];
    #pragma unroll
    for (int g = 0; g < GRP; ++g) gw[g] = pk[(size_t)g * B_SIZE];

    float4* op = out4 + (size_t)t0 * B_SIZE + b;

    #pragma unroll
    for (int g = 0; g < GRP; ++g) {
        const uint32_t w = gw[g];
        #pragma unroll
        for (int i = 0; i < 8; ++i) {
            const int   code = (int)((w >> (4*i)) & 0xFu);
            const int   c    = code & 3;
            const float r    = (float)((code >> 2) & 1);

            const float target = fmaf(r, gp1, -gam);
            const bool e0=(c==0), e1=(c==1), e2=(c==2), e3=(c==3);
            q0 = e0 ? target : q0;
            q1 = e1 ? target : q1;
            q2 = e2 ? target : q2;
            q3 = e3 ? target : q3;

            const bool same = (c == old_c);
            tsls_i = same ? tsls_i + 1 : 0;
            er *= ER_DECAY;

            const int nch = e0 ? n0+1 : (e1 ? n1+1 : (e2 ? n2+1 : n3+1));
            const float lnch = ln1p[nch];
            n0 += e0; n1 += e1; n2 += e2; n3 += e3;
            ln0  = e0 ? lnch : ln0;
            ln1_ = e1 ? lnch : ln1_;
            ln2_ = e2 ? lnch : ln2_;
            ln3_ = e3 ? lnch : ln3_;

            const float qm = 0.25f * ((q0+q1)+(q2+q3));
            q0 = decay * fmaf(er, qm - q0, q0);
            q1 = decay * fmaf(er, qm - q1, q1);
            q2 = decay * fmaf(er, qm - q2, q2);
            q3 = decay * fmaf(er, qm - q3, q3);

            const float s0 = fmaf(bt, q0, beta_p * ln0);
            const float s1 = fmaf(bt, q1, beta_p * ln1_);
            const float s2 = fmaf(bt, q2, beta_p * ln2_);
            const float s3 = fmaf(bt, q3, beta_p * ln3_);

            const float m  = fmaxf(fmaxf(s0, s1), fmaxf(s2, s3));
            const float x0 = __expf(s0 - m);
            const float x1 = __expf(s1 - m);
            const float x2 = __expf(s2 - m);
            const float x3 = __expf(s3 - m);
            const float inv = __builtin_amdgcn_rcpf((x0+x1)+(x2+x3));
            const float sc  = ol * inv;

            float l0 = __logf(fmaf(sc, x0, la4));
            float l1 = __logf(fmaf(sc, x1, la4));
            float l2 = __logf(fmaf(sc, x2, la4));
            float l3 = __logf(fmaf(sc, x3, la4));

            const float bonus = (same ? perv : sw) + ln1p[tsls_i];
            l0 += e0 ? bonus : 0.0f;
            l1 += e1 ? bonus : 0.0f;
            l2 += e2 ? bonus : 0.0f;
            l3 += e3 ? bonus : 0.0f;

            l0 += (old_c == 0) ? ab1 : 0.0f;
            l1 += (old_c == 1) ? ab1 : 0.0f;
            l2 += (old_c == 2) ? ab1 : 0.0f;
            l3 += (old_c == 3) ? ab1 : 0.0f;

            const int c2 = (c + 2) & 3;
            l0 += (c2 == 0) ? ab2 : 0.0f;
            l1 += (c2 == 1) ? ab2 : 0.0f;
            l2 += (c2 == 2) ? ab2 : 0.0f;
            l3 += (c2 == 3) ? ab2 : 0.0f;

            f32x4_t v = {l0, l1, l2, l3};
            __builtin_nontemporal_store(v, reinterpret_cast<f32x4_t*>(op + (size_t)(g*8 + i) * B_SIZE));
            old_c = c;
        }
    }
}

// ===========================================================================
// FALLBACK: round-1 monolithic scan (only if workspace is too small).
// ===========================================================================
__global__ __launch_bounds__(64)
void castro_scan(const float* __restrict__ params,
                 const float* __restrict__ rewards,
                 const int*   __restrict__ choices,
                 const int*   __restrict__ pids,
                 float*       __restrict__ out)
{
    const int b = blockIdx.x * blockDim.x + threadIdx.x;
    if (b >= B_SIZE) return;
    const int pid = pids[b];
    float p[13];
    #pragma unroll
    for (int kk = 0; kk < 13; ++kk)
        p[kk] = clampf(params[kk * P_SIZE + pid], -5.0f, 5.0f);
    const float beta_r   = clampf(sp_(p[0]), 0.01f, 20.0f);
    const float lapse    = clampf(sg_(p[1]), 0.01f, 0.99f);
    const float prior    = clampf(sp_(p[2]), 0.01f, 0.99f);
    const float alpha_er = clampf(sg_(p[3]), 0.01f, 0.99f);
    const float decay    = clampf(sg_(p[4]), 0.01f, 0.99f);
    const float ab1 = p[5], ab2 = p[6];
    const float perv = sp_(p[7]), sw = p[8];
    const float gam  = sp_(p[10]);
    const float temp = clampf(sp_(p[11]) + 1e-6f, 1e-6f, 100.0f);
    const float beta_p = sp_(p[12]);
    const float bt = beta_r / temp, ol = 1.0f - lapse, la4 = 0.25f * lapse, gp1 = 1.0f + gam;

    float q0=prior,q1=prior,q2=prior,q3=prior;
    float n0=0,n1=0,n2=0,n3=0;
    int old_c=-1; float tsls=0.0f, er=alpha_er;
    const int* cp = choices + b;
    const float* rp = rewards + b;
    float4* op = reinterpret_cast<float4*>(out) + b;
    for (int t = 0; t < T_TRIALS; ++t) {
        const int c = cp[(size_t)t*B_SIZE];
        const float r = rp[(size_t)t*B_SIZE];
        const float target = fmaf(r, gp1, -gam);
        const bool e0=(c==0),e1=(c==1),e2=(c==2),e3=(c==3);
        q0=e0?target:q0; q1=e1?target:q1; q2=e2?target:q2; q3=e3?target:q3;
        const bool same = (c == old_c);
        tsls = same ? tsls + 1.0f : 0.0f;
        er *= ER_DECAY;
        n0+=e0?1.f:0.f; n1+=e1?1.f:0.f; n2+=e2?1.f:0.f; n3+=e3?1.f:0.f;
        const float qm = 0.25f*((q0+q1)+(q2+q3));
        q0 = decay*fmaf(er, qm-q0, q0); q1 = decay*fmaf(er, qm-q1, q1);
        q2 = decay*fmaf(er, qm-q2, q2); q3 = decay*fmaf(er, qm-q3, q3);
        float s0 = fmaf(bt,q0,beta_p*__logf(1.f+n0));
        float s1 = fmaf(bt,q1,beta_p*__logf(1.f+n1));
        float s2 = fmaf(bt,q2,beta_p*__logf(1.f+n2));
        float s3 = fmaf(bt,q3,beta_p*__logf(1.f+n3));
        const float m = fmaxf(fmaxf(s0,s1),fmaxf(s2,s3));
        const float x0=__expf(s0-m),x1=__expf(s1-m),x2=__expf(s2-m),x3=__expf(s3-m);
        const float inv=__builtin_amdgcn_rcpf((x0+x1)+(x2+x3));
        const float sc=ol*inv;
        float l0=__logf(fmaf(sc,x0,la4)), l1=__logf(fmaf(sc,x1,la4));
        float l2=__logf(fmaf(sc,x2,la4)), l3=__logf(fmaf(sc,x3,la4));
        const float bonus=(same?perv:sw)+__logf(tsls+1.0f);
        l0+=e0?bonus:0.f; l1+=e1?bonus:0.f; l2+=e2?bonus:0.f; l3+=e3?bonus:0.f;
        l0+=(old_c==0)?ab1:0.f; l1+=(old_c==1)?ab1:0.f; l2+=(old_c==2)?ab1:0.f; l3+=(old_c==3)?ab1:0.f;
        const int c2=(c+2)&3;
        l0+=(c2==0)?ab2:0.f; l1+=(c2==1)?ab2:0.f; l2+=(c2==2)?ab2:0.f; l3+=(c2==3)?ab2:0.f;
        op[(size_t)t*B_SIZE] = make_float4(l0,l1,l2,l3);
        old_c=c;
    }
}

extern "C" void kernel_launch(void* const* d_in, const int* in_sizes, int n_in,
                              void* d_out, int out_size, void* d_ws, size_t ws_size,
                              hipStream_t stream)
{
    const float* params  = (const float*)d_in[0];
    const float* rewards = (const float*)d_in[1];
    const int*   choices = (const int*)  d_in[2];
    const int*   pids    = (const int*)  d_in[3];

    // stageA: 6*NMAPS*B float4 | cps: 2*NMAPS*B float4 | packed: (T/8)*B u32
    const size_t need_p = (size_t)NMAPS * B_SIZE * 96
                        + (size_t)NMAPS * B_SIZE * 32
                        + (size_t)(T_TRIALS/8) * B_SIZE * 4;

    if (ws_size >= need_p) {
        float4*   stageA = (float4*)d_ws;
        float4*   cps    = stageA + (size_t)6 * NMAPS * B_SIZE;
        uint32_t* packed = (uint32_t*)(cps + (size_t)2 * NMAPS * B_SIZE);

        hipLaunchKernelGGL(castro_chunkmap_p, dim3(B_SIZE/256, KCH), dim3(256), 0, stream,
                           params, rewards, choices, pids, stageA, packed);
        hipLaunchKernelGGL(castro_combine_p, dim3(B_SIZE/256), dim3(256), 0, stream,
                           params, pids, stageA, cps);
        hipLaunchKernelGGL(castro_emit_p, dim3(B_SIZE/256, KCH), dim3(256), 0, stream,
                           params, pids, cps, packed, (float4*)d_out);
        return;
    }

    hipLaunchKernelGGL(castro_scan, dim3(B_SIZE/64), dim3(64), 0, stream,
                       params, rewards, choices, pids, (float*)d_out);
}

// Round 5
// 69.539 us; speedup vs baseline: 6.1812x; 1.1683x over previous
//
#include <hip/hip_runtime.h>
#include <stdint.h>

#define T_TRIALS 1000
#define B_SIZE   8192
#define P_SIZE   1024
#define NGROUPS  125           // T/8 packed u32 groups total
#define ER_DECAY 0.999f
#define LN_ER_DECAY (-1.0005003335835335e-3f)
#define LOG2E_F 1.4426950408889634f
#define LN2_F   0.69314718055994531f

typedef float f32x4_t __attribute__((ext_vector_type(4)));

__device__ __forceinline__ float sp_(float x){ return __logf(1.0f + __expf(x)); }   // softplus
__device__ __forceinline__ float sg_(float x){ return 1.0f / (1.0f + __expf(-x)); } // sigmoid
__device__ __forceinline__ float clampf(float x, float lo, float hi){ return fminf(fmaxf(x, lo), hi); }

// ===========================================================================
// Kernel 1a: per-chunk affine map composition + 4-bit (choice,reward) packing
// ===========================================================================
template<int CHUNK_T, int KCH_T>
__global__ __launch_bounds__(256)
void castro_chunkmap_t(const float* __restrict__ params,
                       const float* __restrict__ rewards,
                       const int*   __restrict__ choices,
                       const int*   __restrict__ pids,
                       float4*      __restrict__ stageA,   // [6][NM*B]
                       uint32_t*    __restrict__ packed)   // [NGROUPS*B]
{
    constexpr int NM    = KCH_T - 1;
    constexpr int GRP_T = CHUNK_T / 8;
    constexpr int TAILG = (T_TRIALS - NM * CHUNK_T) / 8;

    const int b  = blockIdx.x * 256 + threadIdx.x;
    const int k  = blockIdx.y;
    const int t0 = k * CHUNK_T;

    const int*   cp = choices + (size_t)t0 * B_SIZE + b;
    const float* rp = rewards + (size_t)t0 * B_SIZE + b;
    uint32_t*    pk = packed + (size_t)(k * GRP_T) * B_SIZE + b;

    if (k == NM) {   // last chunk: its map is never consumed — pack only
        #pragma unroll
        for (int g = 0; g < GRP_T; ++g) {
            if (g < TAILG) {
                uint32_t gw = 0;
                #pragma unroll
                for (int i = 0; i < 8; ++i) {
                    const int   c = cp[(size_t)(g*8 + i) * B_SIZE];
                    const float r = rp[(size_t)(g*8 + i) * B_SIZE];
                    gw |= ((uint32_t)c | (r > 0.5f ? 4u : 0u)) << (4*i);
                }
                pk[(size_t)g * B_SIZE] = gw;
            }
        }
        return;
    }

    const int pid = pids[b];
    const float p3  = clampf(params[ 3 * P_SIZE + pid], -5.0f, 5.0f);
    const float p4  = clampf(params[ 4 * P_SIZE + pid], -5.0f, 5.0f);
    const float p10 = clampf(params[10 * P_SIZE + pid], -5.0f, 5.0f);
    const float alpha_er = clampf(sg_(p3), 0.01f, 0.99f);
    const float decay    = clampf(sg_(p4), 0.01f, 0.99f);
    const float gam      = sp_(p10);
    const float gp1      = 1.0f + gam;

    float er = alpha_er * __expf((float)t0 * LN_ER_DECAY);

    float m00=1.f,m01=0.f,m02=0.f,m03=0.f;
    float m10=0.f,m11=1.f,m12=0.f,m13=0.f;
    float m20=0.f,m21=0.f,m22=1.f,m23=0.f;
    float m30=0.f,m31=0.f,m32=0.f,m33=1.f;
    float b0=0.f,b1=0.f,b2=0.f,b3=0.f;
    int   c0=0,c1=0,c2=0,c3=0;
    int   run=0, last=-1;

    #pragma unroll
    for (int g = 0; g < GRP_T; ++g) {
        int cc[8]; float rr[8];
        #pragma unroll
        for (int i = 0; i < 8; ++i) {
            cc[i] = cp[(size_t)(g*8 + i) * B_SIZE];
            rr[i] = rp[(size_t)(g*8 + i) * B_SIZE];
        }
        uint32_t gw = 0;
        #pragma unroll
        for (int i = 0; i < 8; ++i) {
            const int   c = cc[i];
            const float r = rr[i];
            gw |= ((uint32_t)c | (r > 0.5f ? 4u : 0u)) << (4*i);

            er *= ER_DECAY;
            const float target = fmaf(r, gp1, -gam);
            const bool e0=(c==0), e1=(c==1), e2=(c==2), e3=(c==3);

            m00=e0?0.f:m00; m01=e0?0.f:m01; m02=e0?0.f:m02; m03=e0?0.f:m03; b0=e0?target:b0;
            m10=e1?0.f:m10; m11=e1?0.f:m11; m12=e1?0.f:m12; m13=e1?0.f:m13; b1=e1?target:b1;
            m20=e2?0.f:m20; m21=e2?0.f:m21; m22=e2?0.f:m22; m23=e2?0.f:m23; b2=e2?target:b2;
            m30=e3?0.f:m30; m31=e3?0.f:m31; m32=e3?0.f:m32; m33=e3?0.f:m33; b3=e3?target:b3;

            const float s0=(m00+m10)+(m20+m30);
            const float s1=(m01+m11)+(m21+m31);
            const float s2=(m02+m12)+(m22+m32);
            const float s3=(m03+m13)+(m23+m33);
            const float sb=(b0+b1)+(b2+b3);
            const float a  = decay * (1.0f - er);
            const float e4 = decay * er * 0.25f;

            m00=fmaf(e4,s0,a*m00); m01=fmaf(e4,s1,a*m01); m02=fmaf(e4,s2,a*m02); m03=fmaf(e4,s3,a*m03);
            m10=fmaf(e4,s0,a*m10); m11=fmaf(e4,s1,a*m11); m12=fmaf(e4,s2,a*m12); m13=fmaf(e4,s3,a*m13);
            m20=fmaf(e4,s0,a*m20); m21=fmaf(e4,s1,a*m21); m22=fmaf(e4,s2,a*m22); m23=fmaf(e4,s3,a*m23);
            m30=fmaf(e4,s0,a*m30); m31=fmaf(e4,s1,a*m31); m32=fmaf(e4,s2,a*m32); m33=fmaf(e4,s3,a*m33);
            b0=fmaf(e4,sb,a*b0); b1=fmaf(e4,sb,a*b1); b2=fmaf(e4,sb,a*b2); b3=fmaf(e4,sb,a*b3);

            c0 += e0; c1 += e1; c2 += e2; c3 += e3;
            run = (c == last) ? run + 1 : 1;
            last = c;
        }
        pk[(size_t)g * B_SIZE] = gw;
    }

    const size_t idx    = (size_t)k * B_SIZE + b;
    const size_t stride = (size_t)NM * B_SIZE;
    stageA[0*stride+idx] = make_float4(m00,m01,m02,m03);
    stageA[1*stride+idx] = make_float4(m10,m11,m12,m13);
    stageA[2*stride+idx] = make_float4(m20,m21,m22,m23);
    stageA[3*stride+idx] = make_float4(m30,m31,m32,m33);
    stageA[4*stride+idx] = make_float4(b0,b1,b2,b3);
    const unsigned meta0 = (unsigned)c0 | ((unsigned)c1<<8) | ((unsigned)c2<<16) | ((unsigned)c3<<24);
    const unsigned meta1 = (unsigned)last | ((unsigned)run<<8);
    stageA[5*stride+idx] = make_float4(__uint_as_float(meta0), __uint_as_float(meta1), 0.f, 0.f);
}

// ===========================================================================
// Kernel 1b: sequential combine over chunk maps -> checkpoints (2 planes)
// ===========================================================================
struct MapSet { float4 r0, r1, r2, r3, r4, r5; };
struct CombSt { float q0,q1,q2,q3; int n0,n1,n2,n3; int g_run, g_last; };

template<int NM>
__device__ __forceinline__ void load_set(MapSet& S, const float4* __restrict__ stageA, int kk, int b)
{
    const size_t stride = (size_t)NM * B_SIZE;
    const size_t i2 = (size_t)kk * B_SIZE + b;
    S.r0 = stageA[i2];          S.r1 = stageA[stride+i2];   S.r2 = stageA[2*stride+i2];
    S.r3 = stageA[3*stride+i2]; S.r4 = stageA[4*stride+i2]; S.r5 = stageA[5*stride+i2];
}

template<int CHUNK_T>
__device__ __forceinline__ void step_set(const MapSet& S, CombSt& st,
                                         float4* __restrict__ cpsA,
                                         float4* __restrict__ cpsB,
                                         float alpha_er, int kk, int b)
{
    const float nq0 = fmaf(S.r0.w,st.q3, fmaf(S.r0.z,st.q2, fmaf(S.r0.y,st.q1, fmaf(S.r0.x,st.q0, S.r4.x))));
    const float nq1 = fmaf(S.r1.w,st.q3, fmaf(S.r1.z,st.q2, fmaf(S.r1.y,st.q1, fmaf(S.r1.x,st.q0, S.r4.y))));
    const float nq2 = fmaf(S.r2.w,st.q3, fmaf(S.r2.z,st.q2, fmaf(S.r2.y,st.q1, fmaf(S.r2.x,st.q0, S.r4.z))));
    const float nq3 = fmaf(S.r3.w,st.q3, fmaf(S.r3.z,st.q2, fmaf(S.r3.y,st.q1, fmaf(S.r3.x,st.q0, S.r4.w))));
    st.q0=nq0; st.q1=nq1; st.q2=nq2; st.q3=nq3;

    const unsigned meta0 = __float_as_uint(S.r5.x);
    const unsigned meta1 = __float_as_uint(S.r5.y);
    st.n0 += (int)( meta0        & 255u);
    st.n1 += (int)((meta0 >> 8 ) & 255u);
    st.n2 += (int)((meta0 >> 16) & 255u);
    st.n3 += (int)( meta0 >> 24        );
    const int last = (int)(meta1 & 255u);
    const int rn   = (int)(meta1 >> 8);
    st.g_run  = (rn == CHUNK_T && last == st.g_last) ? st.g_run + CHUNK_T : rn;
    st.g_last = last;

    const float er_b = alpha_er * __expf((float)((kk+1)*CHUNK_T) * LN_ER_DECAY);
    const int   tsls = st.g_run - 1;

    const size_t ci = (size_t)kk * B_SIZE + b;
    cpsA[ci] = make_float4(st.q0,st.q1,st.q2,st.q3);
    cpsB[ci] = make_float4(er_b,
                           __uint_as_float((unsigned)st.n0 | ((unsigned)st.n1<<16)),
                           __uint_as_float((unsigned)st.n2 | ((unsigned)st.n3<<16)),
                           __uint_as_float((unsigned)tsls | ((unsigned)st.g_last<<16)));
}

template<int CHUNK_T, int KCH_T>
__global__ __launch_bounds__(64)
void castro_combine_t(const float* __restrict__ params,
                      const int*   __restrict__ pids,
                      const float4* __restrict__ stageA,
                      float4*      __restrict__ cpsA,
                      float4*      __restrict__ cpsB)
{
    constexpr int NM  = KCH_T - 1;
    constexpr int NM4 = ((NM + 3) / 4) * 4;

    const int b = blockIdx.x * 64 + threadIdx.x;
    const int pid = pids[b];
    const float p2 = clampf(params[2 * P_SIZE + pid], -5.0f, 5.0f);
    const float p3 = clampf(params[3 * P_SIZE + pid], -5.0f, 5.0f);
    const float prior    = clampf(sp_(p2), 0.01f, 0.99f);
    const float alpha_er = clampf(sg_(p3), 0.01f, 0.99f);

    CombSt st;
    st.q0=prior; st.q1=prior; st.q2=prior; st.q3=prior;
    st.n0=0; st.n1=0; st.n2=0; st.n3=0;
    st.g_run=0; st.g_last=-1;

    MapSet Am, Bm, Cm, Dm;
    load_set<NM>(Am, stageA, 0, b);
    load_set<NM>(Bm, stageA, 1, b);
    load_set<NM>(Cm, stageA, 2, b);
    load_set<NM>(Dm, stageA, 3, b);

    #pragma unroll
    for (int k0 = 0; k0 < NM4; k0 += 4) {
        if (k0   < NM) { step_set<CHUNK_T>(Am, st, cpsA, cpsB, alpha_er, k0,   b); if (k0+4 < NM) load_set<NM>(Am, stageA, k0+4, b); }
        if (k0+1 < NM) { step_set<CHUNK_T>(Bm, st, cpsA, cpsB, alpha_er, k0+1, b); if (k0+5 < NM) load_set<NM>(Bm, stageA, k0+5, b); }
        if (k0+2 < NM) { step_set<CHUNK_T>(Cm, st, cpsA, cpsB, alpha_er, k0+2, b); if (k0+6 < NM) load_set<NM>(Cm, stageA, k0+6, b); }
        if (k0+3 < NM) { step_set<CHUNK_T>(Dm, st, cpsA, cpsB, alpha_er, k0+3, b); if (k0+7 < NM) load_set<NM>(Dm, stageA, k0+7, b); }
    }
}

// ===========================================================================
// Kernel 2: per-chunk logit replay from packed stream (base-2, no LDS)
// ===========================================================================
template<int CHUNK_T, int KCH_T>
__global__ __launch_bounds__(256)
void castro_emit_t(const float* __restrict__ params,
                   const int*   __restrict__ pids,
                   const float4* __restrict__ cpsA,
                   const float4* __restrict__ cpsB,
                   const uint32_t* __restrict__ packed,
                   float4*      __restrict__ out4)
{
    constexpr int GRP_T = CHUNK_T / 8;
    constexpr int TAILG = (T_TRIALS - (KCH_T-1) * CHUNK_T) / 8;

    const int b  = blockIdx.x * 256 + threadIdx.x;
    const int k  = blockIdx.y;
    const int t0 = k * CHUNK_T;
    const int ngroups = (k == KCH_T-1) ? TAILG : GRP_T;
    const int pid = pids[b];

    float p[13];
    #pragma unroll
    for (int kk = 0; kk < 13; ++kk)
        p[kk] = clampf(params[kk * P_SIZE + pid], -5.0f, 5.0f);

    const float beta_r   = clampf(sp_(p[0]), 0.01f, 20.0f);
    const float lapse    = clampf(sg_(p[1]), 0.01f, 0.99f);
    const float prior    = clampf(sp_(p[2]), 0.01f, 0.99f);
    const float alpha_er = clampf(sg_(p[3]), 0.01f, 0.99f);
    const float decay    = clampf(sg_(p[4]), 0.01f, 0.99f);
    const float ab1      = p[5];
    const float ab2      = p[6];
    const float perv     = sp_(p[7]);
    const float sw       = p[8];
    const float gam      = sp_(p[10]);
    const float temp     = clampf(sp_(p[11]) + 1e-6f, 1e-6f, 100.0f);
    const float beta_p   = sp_(p[12]);

    const float bt2 = (beta_r / temp) * LOG2E_F;   // base-2 q coefficient
    const float ol  = 1.0f - lapse;
    const float la4 = 0.25f * lapse;
    const float gp1 = 1.0f + gam;

    float q0,q1,q2,q3, er, ft;
    float f0,f1,f2,f3;           // cumulative counts as floats
    int   old_c;
    if (k == 0) {
        q0=q1=q2=q3=prior; f0=f1=f2=f3=0.f; ft=-1.f; old_c=-1; er=alpha_er;
        // ft is tsls; we store tsls directly (init 0 handled below via same=false)
        ft = 0.f;
    } else {
        const size_t ci = (size_t)(k-1) * B_SIZE + b;
        const float4 s0 = cpsA[ci];
        const float4 s1 = cpsB[ci];
        q0=s0.x; q1=s0.y; q2=s0.z; q3=s0.w;
        er = s1.x;
        const unsigned u1=__float_as_uint(s1.y), u2=__float_as_uint(s1.z), u3=__float_as_uint(s1.w);
        f0=(float)(int)(u1&0xFFFFu); f1=(float)(int)(u1>>16);
        f2=(float)(int)(u2&0xFFFFu); f3=(float)(int)(u2>>16);
        ft=(float)(int)(u3&0xFFFFu); old_c=(int)(u3>>16);
    }
    // bpl_j = beta_p * log2(1 + n_j)
    float bpl0 = beta_p * __log2f(1.0f + f0);
    float bpl1 = beta_p * __log2f(1.0f + f1);
    float bpl2 = beta_p * __log2f(1.0f + f2);
    float bpl3 = beta_p * __log2f(1.0f + f3);

    const uint32_t* pk = packed + (size_t)(k * GRP_T) * B_SIZE + b;
    float4* op = out4 + (size_t)t0 * B_SIZE + b;

    #pragma unroll
    for (int g = 0; g < GRP_T; ++g) {
        if (g < ngroups) {
            const uint32_t w = pk[(size_t)g * B_SIZE];
            #pragma unroll
            for (int i = 0; i < 8; ++i) {
                const int   code = (int)((w >> (4*i)) & 0xFu);
                const int   c    = code & 3;
                const float r    = (float)((code >> 2) & 1);

                const float target = fmaf(r, gp1, -gam);
                const bool e0=(c==0), e1=(c==1), e2=(c==2), e3=(c==3);
                q0 = e0 ? target : q0;
                q1 = e1 ? target : q1;
                q2 = e2 ? target : q2;
                q3 = e3 ? target : q3;

                const bool same = (c == old_c);
                ft = same ? ft + 1.0f : 0.0f;
                er *= ER_DECAY;

                // count update for chosen action; bpl = beta_p*log2(1+n)
                const float fsel = e0 ? f0 : (e1 ? f1 : (e2 ? f2 : f3));
                const float bplc = beta_p * __log2f(fsel + 2.0f);
                f0 += e0 ? 1.0f : 0.0f;
                f1 += e1 ? 1.0f : 0.0f;
                f2 += e2 ? 1.0f : 0.0f;
                f3 += e3 ? 1.0f : 0.0f;
                bpl0 = e0 ? bplc : bpl0;
                bpl1 = e1 ? bplc : bpl1;
                bpl2 = e2 ? bplc : bpl2;
                bpl3 = e3 ? bplc : bpl3;

                const float qm = 0.25f * ((q0+q1)+(q2+q3));
                q0 = decay * fmaf(er, qm - q0, q0);
                q1 = decay * fmaf(er, qm - q1, q1);
                q2 = decay * fmaf(er, qm - q2, q2);
                q3 = decay * fmaf(er, qm - q3, q3);

                // base-2 softmax: s2 = s/ln2
                const float s0 = fmaf(bt2, q0, bpl0);
                const float s1 = fmaf(bt2, q1, bpl1);
                const float s2 = fmaf(bt2, q2, bpl2);
                const float s3 = fmaf(bt2, q3, bpl3);

                const float m  = fmaxf(fmaxf(s0, s1), fmaxf(s2, s3));
                const float x0 = exp2f(s0 - m);
                const float x1 = exp2f(s1 - m);
                const float x2 = exp2f(s2 - m);
                const float x3 = exp2f(s3 - m);
                const float inv = __builtin_amdgcn_rcpf((x0+x1)+(x2+x3));
                const float sc  = ol * inv;

                const float L0 = __log2f(fmaf(sc, x0, la4));
                const float L1 = __log2f(fmaf(sc, x1, la4));
                const float L2 = __log2f(fmaf(sc, x2, la4));
                const float L3 = __log2f(fmaf(sc, x3, la4));

                const float bonus = fmaf(LN2_F, __log2f(ft + 1.0f), same ? perv : sw);

                float a0 = (e0 ? bonus : 0.0f) + ((old_c == 0) ? ab1 : 0.0f);
                float a1 = (e1 ? bonus : 0.0f) + ((old_c == 1) ? ab1 : 0.0f);
                float a2 = (e2 ? bonus : 0.0f) + ((old_c == 2) ? ab1 : 0.0f);
                float a3 = (e3 ? bonus : 0.0f) + ((old_c == 3) ? ab1 : 0.0f);
                const int c2 = (c + 2) & 3;
                a0 += (c2 == 0) ? ab2 : 0.0f;
                a1 += (c2 == 1) ? ab2 : 0.0f;
                a2 += (c2 == 2) ? ab2 : 0.0f;
                a3 += (c2 == 3) ? ab2 : 0.0f;

                f32x4_t v = { fmaf(LN2_F, L0, a0), fmaf(LN2_F, L1, a1),
                              fmaf(LN2_F, L2, a2), fmaf(LN2_F, L3, a3) };
                __builtin_nontemporal_store(v, reinterpret_cast<f32x4_t*>(op + (size_t)(g*8 + i) * B_SIZE));
                old_c = c;
            }
        }
    }
}

// ===========================================================================
// FALLBACK: round-1 monolithic scan (only if workspace is too small).
// ===========================================================================
__global__ __launch_bounds__(64)
void castro_scan(const float* __restrict__ params,
                 const float* __restrict__ rewards,
                 const int*   __restrict__ choices,
                 const int*   __restrict__ pids,
                 float*       __restrict__ out)
{
    const int b = blockIdx.x * blockDim.x + threadIdx.x;
    if (b >= B_SIZE) return;
    const int pid = pids[b];
    float p[13];
    #pragma unroll
    for (int kk = 0; kk < 13; ++kk)
        p[kk] = clampf(params[kk * P_SIZE + pid], -5.0f, 5.0f);
    const float beta_r   = clampf(sp_(p[0]), 0.01f, 20.0f);
    const float lapse    = clampf(sg_(p[1]), 0.01f, 0.99f);
    const float prior    = clampf(sp_(p[2]), 0.01f, 0.99f);
    const float alpha_er = clampf(sg_(p[3]), 0.01f, 0.99f);
    const float decay    = clampf(sg_(p[4]), 0.01f, 0.99f);
    const float ab1 = p[5], ab2 = p[6];
    const float perv = sp_(p[7]), sw = p[8];
    const float gam  = sp_(p[10]);
    const float temp = clampf(sp_(p[11]) + 1e-6f, 1e-6f, 100.0f);
    const float beta_p = sp_(p[12]);
    const float bt = beta_r / temp, ol = 1.0f - lapse, la4 = 0.25f * lapse, gp1 = 1.0f + gam;

    float q0=prior,q1=prior,q2=prior,q3=prior;
    float n0=0,n1=0,n2=0,n3=0;
    int old_c=-1; float tsls=0.0f, er=alpha_er;
    const int* cp = choices + b;
    const float* rp = rewards + b;
    float4* op = reinterpret_cast<float4*>(out) + b;
    for (int t = 0; t < T_TRIALS; ++t) {
        const int c = cp[(size_t)t*B_SIZE];
        const float r = rp[(size_t)t*B_SIZE];
        const float target = fmaf(r, gp1, -gam);
        const bool e0=(c==0),e1=(c==1),e2=(c==2),e3=(c==3);
        q0=e0?target:q0; q1=e1?target:q1; q2=e2?target:q2; q3=e3?target:q3;
        const bool same = (c == old_c);
        tsls = same ? tsls + 1.0f : 0.0f;
        er *= ER_DECAY;
        n0+=e0?1.f:0.f; n1+=e1?1.f:0.f; n2+=e2?1.f:0.f; n3+=e3?1.f:0.f;
        const float qm = 0.25f*((q0+q1)+(q2+q3));
        q0 = decay*fmaf(er, qm-q0, q0); q1 = decay*fmaf(er, qm-q1, q1);
        q2 = decay*fmaf(er, qm-q2, q2); q3 = decay*fmaf(er, qm-q3, q3);
        float s0 = fmaf(bt,q0,beta_p*__logf(1.f+n0));
        float s1 = fmaf(bt,q1,beta_p*__logf(1.f+n1));
        float s2 = fmaf(bt,q2,beta_p*__logf(1.f+n2));
        float s3 = fmaf(bt,q3,beta_p*__logf(1.f+n3));
        const float m = fmaxf(fmaxf(s0,s1),fmaxf(s2,s3));
        const float x0=__expf(s0-m),x1=__expf(s1-m),x2=__expf(s2-m),x3=__expf(s3-m);
        const float inv=__builtin_amdgcn_rcpf((x0+x1)+(x2+x3));
        const float sc=ol*inv;
        float l0=__logf(fmaf(sc,x0,la4)), l1=__logf(fmaf(sc,x1,la4));
        float l2=__logf(fmaf(sc,x2,la4)), l3=__logf(fmaf(sc,x3,la4));
        const float bonus=(same?perv:sw)+__logf(tsls+1.0f);
        l0+=e0?bonus:0.f; l1+=e1?bonus:0.f; l2+=e2?bonus:0.f; l3+=e3?bonus:0.f;
        l0+=(old_c==0)?ab1:0.f; l1+=(old_c==1)?ab1:0.f; l2+=(old_c==2)?ab1:0.f; l3+=(old_c==3)?ab1:0.f;
        const int c2=(c+2)&3;
        l0+=(c2==0)?ab2:0.f; l1+=(c2==1)?ab2:0.f; l2+=(c2==2)?ab2:0.f; l3+=(c2==3)?ab2:0.f;
        op[(size_t)t*B_SIZE] = make_float4(l0,l1,l2,l3);
        old_c=c;
    }
}

// ===========================================================================
template<int CHUNK_T, int KCH_T>
static void launch_pipeline(const float* params, const float* rewards,
                            const int* choices, const int* pids,
                            void* d_out, void* d_ws, hipStream_t stream)
{
    constexpr int NM = KCH_T - 1;
    float4*   stageA = (float4*)d_ws;
    float4*   cpsA   = stageA + (size_t)6 * NM * B_SIZE;
    float4*   cpsB   = cpsA + (size_t)NM * B_SIZE;
    uint32_t* packed = (uint32_t*)(cpsB + (size_t)NM * B_SIZE);

    hipLaunchKernelGGL(HIP_KERNEL_NAME(castro_chunkmap_t<CHUNK_T, KCH_T>),
                       dim3(B_SIZE/256, KCH_T), dim3(256), 0, stream,
                       params, rewards, choices, pids, stageA, packed);
    hipLaunchKernelGGL(HIP_KERNEL_NAME(castro_combine_t<CHUNK_T, KCH_T>),
                       dim3(B_SIZE/64), dim3(64), 0, stream,
                       params, pids, stageA, cpsA, cpsB);
    hipLaunchKernelGGL(HIP_KERNEL_NAME(castro_emit_t<CHUNK_T, KCH_T>),
                       dim3(B_SIZE/256, KCH_T), dim3(256), 0, stream,
                       params, pids, cpsA, cpsB, packed, (float4*)d_out);
}

extern "C" void kernel_launch(void* const* d_in, const int* in_sizes, int n_in,
                              void* d_out, int out_size, void* d_ws, size_t ws_size,
                              hipStream_t stream)
{
    const float* params  = (const float*)d_in[0];
    const float* rewards = (const float*)d_in[1];
    const int*   choices = (const int*)  d_in[2];
    const int*   pids    = (const int*)  d_in[3];

    // workspace: stageA 6*NM*B*16 | cps 2*NM*B*16 | packed NGROUPS*B*4
    const size_t need32 = (size_t)31 * B_SIZE * 128 + (size_t)NGROUPS * B_SIZE * 4;
    const size_t need40 = (size_t)24 * B_SIZE * 128 + (size_t)NGROUPS * B_SIZE * 4;

    if (ws_size >= need32) {
        launch_pipeline<32, 32>(params, rewards, choices, pids, d_out, d_ws, stream);
    } else if (ws_size >= need40) {
        launch_pipeline<40, 25>(params, rewards, choices, pids, d_out, d_ws, stream);
    } else {
        hipLaunchKernelGGL(castro_scan, dim3(B_SIZE/64), dim3(64), 0, stream,
                           params, rewards, choices, pids, (float*)d_out);
    }
}